// Round 13
// baseline (49.438 us; speedup 1.0000x reference)
//
#include <hip/hip_runtime.h>

// LIF forward scan, B=65536 rows x L=400 steps.
// Outputs (concatenated float32 in d_out):
//   [0,              B*L)    spikes (exactly 0.0/1.0)
//   [B*L,        B*L + B)    hard_latency (first spike index, or L) as float
//   [B*L + B,  B*L + 2*B)    soft_latency = sum(s*t) / (sum(s) + 1e-6)
//
// R12: producer-consumer (2 waves/block), pair-level phases, SINGLE input
// buffer (23KB LDS -> 4 blocks/CU resident, R11's 43KB killed this), and
// raw `s_barrier` + lgkmcnt(0)-only sync (NO vmcnt drain): the memory
// wave's pair p+2 loads stay in flight across barriers and are waited
// (counted, by the backend) only at their register use one pair later.
//   phase 1: compute scans pair p from in2; memory expands bits[p-1] -> NT.
//   phase 2: memory puts pair p+1 into in2, issues loads for pair p+2.

constexpr int Bsz    = 65536;
constexpr int Lsz    = 400;
constexpr int ROWS   = 64;          // rows per block (one per compute lane)
constexpr int PW     = 80;          // steps per pair (phase)
constexpr int NPAIR  = 5;
constexpr int STRIDE = 81;          // scan-read bank: (17*l+c)%32 -> 2/bank, free

typedef float floatx4 __attribute__((ext_vector_type(4)));

// barrier WITHOUT vmcnt drain: LDS ordering only (writer's DS ops retired).
#define SYNCB() asm volatile("s_waitcnt lgkmcnt(0)\n\ts_barrier" ::: "memory")

__device__ __forceinline__ int sumpos(unsigned int w) {
    // sum of set-bit positions within a 32-bit word (exact)
    return __popc(w & 0xAAAAAAAAu) + (__popc(w & 0xCCCCCCCCu) << 1) +
           (__popc(w & 0xF0F0F0F0u) << 2) + (__popc(w & 0xFF00FF00u) << 3) +
           (__popc(w & 0xFFFF0000u) << 4);
}

__global__ __launch_bounds__(2 * ROWS)
void lif_kernel(const float* __restrict__ I, float* __restrict__ out)
{
    __shared__ float in2[ROWS * STRIDE];           // 20,736 B (one pair)
    __shared__ unsigned int bits[2][ROWS * 4];     // 2 KiB ping-pong spike bits

    const int tid  = threadIdx.x;
    const int wv   = tid >> 6;       // 0 = compute wave, 1 = memory wave
    const int lane = tid & 63;
    const int rb   = blockIdx.x * ROWS;

    const float* Ib = I   + (size_t)rb * Lsz;
    float*       Sb = out + (size_t)rb * Lsz;

    // ---------------- memory-wave helpers (lane -> linear tile index) ------
    float4 rg[20];                   // one pair (64 rows x 320B)

    auto issue = [&](int p) {        // coalesced: ~17 cache lines per inst
#pragma unroll
        for (int k = 0; k < 20; ++k) {
            const int idx = k * 64 + lane;
            const int r   = idx / 20;
            const int c4  = idx % 20;
            rg[k] = *reinterpret_cast<const float4*>(
                        Ib + (size_t)r * Lsz + p * PW + c4 * 4);
        }
    };
    auto put = [&]() {               // rg -> in2 (stride-81 rows)
#pragma unroll
        for (int k = 0; k < 20; ++k) {
            const int idx = k * 64 + lane;
            const int r   = idx / 20;
            const int c4  = idx % 20;
            float* d = &in2[r * STRIDE + c4 * 4];
            d[0] = rg[k].x; d[1] = rg[k].y; d[2] = rg[k].z; d[3] = rg[k].w;
        }
    };
    auto expand = [&](int p) {       // bits[p&1] -> dense NT float4 stores
        const unsigned int* bl = bits[p & 1];
#pragma unroll
        for (int k = 0; k < 20; ++k) {
            const int idx = k * 64 + lane;
            const int r   = idx / 20;
            const int c4  = idx % 20;
            const unsigned int w = bl[r * 4 + (c4 >> 3)];
            const int bb = (c4 & 7) * 4;
            floatx4 vv = { (float)((w >> (bb + 0)) & 1u),
                           (float)((w >> (bb + 1)) & 1u),
                           (float)((w >> (bb + 2)) & 1u),
                           (float)((w >> (bb + 3)) & 1u) };
            __builtin_nontemporal_store(vv,
                reinterpret_cast<floatx4*>(Sb + (size_t)r * Lsz + p * PW + c4 * 4));
        }
    };

    // ---------------- compute-wave state -----------------------------------
    float v = 0.0f, theta = 1.0f;
    int allow = 0, first = Lsz;
    int cnt_i = 0, swt_i = 0;
    unsigned int w0, w1, w2;
    float rgc[40];

    auto scan40 = [&](const float* src, int t0, int gb) {
#pragma unroll
        for (int c = 0; c < 40; ++c) rgc[c] = src[c];   // batch LDS->reg
#pragma unroll
        for (int c = 0; c < 40; ++c) {
            v = __builtin_fmaf(v, 0.95f, rgc[c]);       // v += -v/20 + I
            const int t = t0 + c;
            const bool hard = (v >= theta) & (t >= allow);
            v     = hard ? 0.0f : v;
            theta = __builtin_fmaf(theta, 0.98f, hard ? 0.52f : 0.02f);
            allow = hard ? (t + 6) : allow;             // 5 blocked steps
            const int cg = gb + c;                      // compile-time
            const unsigned int m = hard ? (1u << (cg & 31)) : 0u;
            if (cg < 32) w0 |= m; else if (cg < 64) w1 |= m; else w2 |= m;
        }
    };

    // ---------------- prologue ---------------------------------------------
    if (wv == 1) {
        issue(0);
        put();                       // full-latency wait, once
        issue(1);                    // stays in flight across barriers
    }
    SYNCB();

    // ---------------- main loop: 2 syncs per pair --------------------------
    for (int pr = 0; pr < NPAIR; ++pr) {
        if (wv == 0) {
            // phase 1: scan pair pr
            const float* src = &in2[lane * STRIDE];
            w0 = w1 = w2 = 0u;
            scan40(src,      pr * PW,      0);
            scan40(src + 40, pr * PW + 40, 40);
            const int tp = pr * PW;
            const int p0 = __popc(w0), p1 = __popc(w1), p2 = __popc(w2);
            const int cp = p0 + p1 + p2;
            cnt_i += cp;
            swt_i += tp * cp + sumpos(w0) + sumpos(w1) + 32 * p1 +
                     sumpos(w2) + 64 * p2;
            const int cand = w0 ? tp + (__ffs(w0) - 1)
                           : w1 ? tp + 32 + (__ffs(w1) - 1)
                           : w2 ? tp + 64 + (__ffs(w2) - 1) : Lsz;
            first = min(first, cand);
            *reinterpret_cast<uint4*>(&bits[pr & 1][lane * 4]) =
                make_uint4(w0, w1, w2, 0u);
        } else {
            // phase 1: write out previous pair's spikes
            if (pr >= 1) expand(pr - 1);
        }
        SYNCB();                     // in2 consumed; bits[pr] published

        if (wv == 1) {
            if (pr + 1 < NPAIR) put();          // rg loads arrived ~1 pair ago
            if (pr + 2 < NPAIR) issue(pr + 2);  // in flight across barriers
        }
        SYNCB();                     // in2 now holds pair pr+1
    }

    // ---------------- epilogue ---------------------------------------------
    if (wv == 1) {
        expand(NPAIR - 1);
    } else {
        const int row = rb + lane;
        out[(size_t)Bsz * Lsz + row]       = (float)first;
        out[(size_t)Bsz * Lsz + Bsz + row] = (float)swt_i / ((float)cnt_i + 1e-6f);
    }
}

extern "C" void kernel_launch(void* const* d_in, const int* in_sizes, int n_in,
                              void* d_out, int out_size, void* d_ws, size_t ws_size,
                              hipStream_t stream)
{
    const float* I = (const float*)d_in[0];
    float* out = (float*)d_out;
    lif_kernel<<<dim3(Bsz / ROWS), dim3(2 * ROWS), 0, stream>>>(I, out);
}

// Round 14
// 36.847 us; speedup vs baseline: 1.3417x; 1.3417x over previous
//
#include <hip/hip_runtime.h>

// LIF forward scan, B=65536 rows x L=400 steps.
// Outputs (concatenated float32 in d_out):
//   [0,              B*L)    spikes (exactly 0.0/1.0)
//   [B*L,        B*L + B)    hard_latency (first spike index, or L) as float
//   [B*L + B,  B*L + 2*B)    soft_latency = sum(s*t) / (sum(s) + 1e-6)
//
// R13 = R10 (best, 37.7us) with ONE change: the memory wave's gather is
// COALESCED (lane -> linear tile index, ~17 cache lines per load inst
// instead of 64 for the own-row gather). The TA/address pipe is shared per
// CU; R10's 4 blocks x 640 lines per phase (~2560 cyc) throttled the CU even
// though the gather sat on the off-path wave. Everything else is identical.

constexpr int Bsz  = 65536;
constexpr int Lsz  = 400;
constexpr int ROWS = 64;            // rows per block (one per compute lane)
constexpr int TC   = 40;            // timesteps per chunk (phase)
constexpr int STRIDE = 41;          // in2 row stride: (9*lane+c)%32 -> 2/bank, free
constexpr int V4   = TC / 4;        // 10 float4 per chunk per row

typedef float floatx4 __attribute__((ext_vector_type(4)));

__device__ __forceinline__ int sumpos(unsigned int w) {
    // sum of set-bit positions within a 32-bit word (exact)
    return __popc(w & 0xAAAAAAAAu) + (__popc(w & 0xCCCCCCCCu) << 1) +
           (__popc(w & 0xF0F0F0F0u) << 2) + (__popc(w & 0xFF00FF00u) << 3) +
           (__popc(w & 0xFFFF0000u) << 4);
}

__global__ __launch_bounds__(2 * ROWS)
void lif_kernel(const float* __restrict__ I, float* __restrict__ out)
{
    __shared__ float in2[2][ROWS * STRIDE];        // 2 x 10,496 B input staging
    __shared__ unsigned int bits[2][ROWS * 4];     // 2 x 1 KiB spike bits

    const int tid  = threadIdx.x;
    const int wv   = tid >> 6;       // 0 = compute wave, 1 = memory wave
    const int lane = tid & 63;
    const int rb   = blockIdx.x * ROWS;

    if (wv == 1) {
        // ------------------------- memory wave -------------------------
        const float* Ib = I   + (size_t)rb * Lsz;
        float*       Sb = out + (size_t)rb * Lsz;
        float4 rg[V4];               // one chunk (64 rows x 160B), lane-linear

        auto issue = [&](int ch) {   // coalesced: idx=k*64+lane, ~17 lines/inst
#pragma unroll
            for (int k = 0; k < V4; ++k) {
                const int idx = k * 64 + lane;
                const int r   = idx / V4;
                const int c4  = idx % V4;
                rg[k] = *reinterpret_cast<const float4*>(
                            Ib + (size_t)r * Lsz + ch * TC + c4 * 4);
            }
        };
        auto put = [&](int buf) {    // rg -> in2[buf] ([row][41] layout)
#pragma unroll
            for (int k = 0; k < V4; ++k) {
                const int idx = k * 64 + lane;
                const int r   = idx / V4;
                const int c4  = idx % V4;
                float* d = &in2[buf][r * STRIDE + c4 * 4];
                d[0] = rg[k].x; d[1] = rg[k].y; d[2] = rg[k].z; d[3] = rg[k].w;
            }
        };
        auto expand_half = [&](int pair, int half) {   // 10 of 20 float4/row
            const unsigned int* bl = bits[pair & 1];
#pragma unroll
            for (int q = 0; q < 10; ++q) {
                const int it  = half * 10 + q;
                const int idx = it * ROWS + lane;
                const int r   = idx / 20;
                const int c4  = idx % 20;
                const unsigned int word = bl[r * 4 + (c4 >> 3)];
                const int bb = (c4 & 7) * 4;
                floatx4 vv = { (float)((word >> (bb + 0)) & 1u),
                               (float)((word >> (bb + 1)) & 1u),
                               (float)((word >> (bb + 2)) & 1u),
                               (float)((word >> (bb + 3)) & 1u) };
                __builtin_nontemporal_store(vv,
                    reinterpret_cast<floatx4*>(Sb + (size_t)r * Lsz + pair * 80 + c4 * 4));
            }
        };

        issue(0); put(0); issue(1);          // ch0 staged; ch1 in flight
        __syncthreads();
        for (int pr = 0; pr < 5; ++pr) {
            const int ch = 2 * pr;
            // phase A (compute scans ch): stage ch+1, issue ch+2, expand prev pair
            put(1);
            if (ch + 2 < 10) issue(ch + 2);
            if (pr >= 1) expand_half(pr - 1, 0);
            __syncthreads();
            // phase B (compute scans ch+1): stage ch+2, issue ch+3, expand rest
            if (ch + 2 < 10) put(0);
            if (ch + 3 < 10) issue(ch + 3);
            if (pr >= 1) expand_half(pr - 1, 1);
            __syncthreads();
        }
        expand_half(4, 0); expand_half(4, 1);          // last pair
    } else {
        // ------------------------- compute wave ------------------------
        float v = 0.0f, theta = 1.0f;
        int allow = 0, first = Lsz;
        int cnt_i = 0, swt_i = 0;            // integer-exact reductions
        unsigned int w0, w1, w2;

        // scan one 40-step chunk; gb = bit offset within pair (LITERAL 0/40)
        auto scan_chunk = [&](int buf, int t0, int gb) {
            const float* src = &in2[buf][lane * STRIDE];
            float rg[TC];
#pragma unroll
            for (int c = 0; c < TC; ++c) rg[c] = src[c];   // batch LDS->reg
#pragma unroll
            for (int c = 0; c < TC; ++c) {
                v = __builtin_fmaf(v, 0.95f, rg[c]);       // v += -v/20 + I
                const int t = t0 + c;
                const bool hard = (v >= theta) & (t >= allow);
                v     = hard ? 0.0f : v;
                theta = __builtin_fmaf(theta, 0.98f, hard ? 0.52f : 0.02f);
                allow = hard ? (t + 6) : allow;            // 5 blocked steps
                const int cg = gb + c;                     // compile-time
                const unsigned int m = hard ? (1u << (cg & 31)) : 0u;
                if (cg < 32) w0 |= m; else if (cg < 64) w1 |= m; else w2 |= m;
            }
        };

        __syncthreads();                      // matches memory prologue barrier
        for (int pr = 0; pr < 5; ++pr) {
            w0 = w1 = w2 = 0u;
            scan_chunk(0, 2 * pr * TC, 0);
            __syncthreads();
            scan_chunk(1, (2 * pr + 1) * TC, TC);
            // pair-end reductions (exact) + publish bits for the memory wave
            const int tp = pr * 80;
            const int p0 = __popc(w0), p1 = __popc(w1), p2 = __popc(w2);
            const int cp = p0 + p1 + p2;
            cnt_i += cp;
            swt_i += tp * cp + sumpos(w0) + sumpos(w1) + 32 * p1 +
                     sumpos(w2) + 64 * p2;
            const int cand = w0 ? tp + (__ffs(w0) - 1)
                           : w1 ? tp + 32 + (__ffs(w1) - 1)
                           : w2 ? tp + 64 + (__ffs(w2) - 1) : Lsz;
            first = min(first, cand);
            *reinterpret_cast<uint4*>(&bits[pr & 1][lane * 4]) =
                make_uint4(w0, w1, w2, 0u);
            __syncthreads();
        }
        const int row = rb + lane;
        out[(size_t)Bsz * Lsz + row]       = (float)first;
        out[(size_t)Bsz * Lsz + Bsz + row] = (float)swt_i / ((float)cnt_i + 1e-6f);
    }
}

extern "C" void kernel_launch(void* const* d_in, const int* in_sizes, int n_in,
                              void* d_out, int out_size, void* d_ws, size_t ws_size,
                              hipStream_t stream)
{
    const float* I = (const float*)d_in[0];
    float* out = (float*)d_out;
    lif_kernel<<<dim3(Bsz / ROWS), dim3(2 * ROWS), 0, stream>>>(I, out);
}

// Round 15
// 35.700 us; speedup vs baseline: 1.3848x; 1.0321x over previous
//
#include <hip/hip_runtime.h>

// LIF forward scan, B=65536 rows x L=400 steps.
// Outputs (concatenated float32 in d_out):
//   [0,              B*L)    spikes (exactly 0.0/1.0)
//   [B*L,        B*L + B)    hard_latency (first spike index, or L) as float
//   [B*L + B,  B*L + 2*B)    soft_latency = sum(s*t) / (sum(s) + 1e-6)
//
// R14 = R13 (best, 36.8us) with the memory wave's {global->reg + 80x
// ds_write put()} replaced by direct global_load_lds DMA (10 insts/chunk,
// no register round-trip), issued one full phase ahead of consumption.
// global_load_lds needs a LINEAR LDS dest, so the stride-41 pad is replaced
// by a both-sides XOR swizzle (rule #21): LDS linear [64][40], global
// SOURCE float4-index XOR'd (j^=((r>>2)&7) for j<8; 16B blocks stay
// contiguous), compute READ applies the same XOR -> ds_read_b128 with
// uniform bank load (unswizzled linear would be 16-way conflicted).

constexpr int Bsz  = 65536;
constexpr int Lsz  = 400;
constexpr int ROWS = 64;            // rows per block (one per compute lane)
constexpr int TC   = 40;            // timesteps per chunk (phase)
constexpr int V4   = TC / 4;        // 10 float4 per chunk per row

typedef float floatx4 __attribute__((ext_vector_type(4)));

__device__ __forceinline__ int sumpos(unsigned int w) {
    // sum of set-bit positions within a 32-bit word (exact)
    return __popc(w & 0xAAAAAAAAu) + (__popc(w & 0xCCCCCCCCu) << 1) +
           (__popc(w & 0xF0F0F0F0u) << 2) + (__popc(w & 0xFF00FF00u) << 3) +
           (__popc(w & 0xFFFF0000u) << 4);
}

__device__ __forceinline__ void dma16(const float* g, float* l)
{
    // lane writes 16B at (uniform l) + lane*16; global src is per-lane.
    __builtin_amdgcn_global_load_lds(
        (const __attribute__((address_space(1))) void*)g,
        (__attribute__((address_space(3))) void*)l,
        16, 0, 0);
}

__global__ __launch_bounds__(2 * ROWS)
void lif_kernel(const float* __restrict__ I, float* __restrict__ out)
{
    __shared__ float in2[2][ROWS * TC];            // 2 x 10,240 B, linear [64][40]
    __shared__ unsigned int bits[2][ROWS * 4];     // 2 x 1 KiB spike bits

    const int tid  = threadIdx.x;
    const int wv   = tid >> 6;       // 0 = compute wave, 1 = memory wave
    const int lane = tid & 63;
    const int rb   = blockIdx.x * ROWS;

    if (wv == 1) {
        // ------------------------- memory wave -------------------------
        const float* Ib = I   + (size_t)rb * Lsz;
        float*       Sb = out + (size_t)rb * Lsz;

        // DMA inst k stages LDS float4-slots [64k, 64k+64); slot s=64k+lane
        // maps to (r = s/10, j' = s%10); source holds global float4
        // j = (j'<8) ? j'^((r>>2)&7) : j'  (XOR self-inverse; 16B blocks
        // contiguous; line-level coalescing ~17 lines/inst preserved).
        int goff[V4];
#pragma unroll
        for (int k = 0; k < V4; ++k) {
            const int s  = k * 64 + lane;
            const int r  = s / 10;
            const int jp = s % 10;
            const int jg = (jp < 8) ? (jp ^ ((r >> 2) & 7)) : jp;
            goff[k] = r * Lsz + jg * 4;
        }
        auto dma = [&](int ch, int buf) {
#pragma unroll
            for (int k = 0; k < V4; ++k)
                dma16(Ib + goff[k] + ch * TC, &in2[buf][k * 256]);
        };
        auto expand_half = [&](int pair, int half) {   // 10 of 20 float4/row
            const unsigned int* bl = bits[pair & 1];
#pragma unroll
            for (int q = 0; q < 10; ++q) {
                const int it  = half * 10 + q;
                const int idx = it * ROWS + lane;
                const int r   = idx / 20;
                const int c4  = idx % 20;
                const unsigned int word = bl[r * 4 + (c4 >> 3)];
                const int bb = (c4 & 7) * 4;
                floatx4 vv = { (float)((word >> (bb + 0)) & 1u),
                               (float)((word >> (bb + 1)) & 1u),
                               (float)((word >> (bb + 2)) & 1u),
                               (float)((word >> (bb + 3)) & 1u) };
                __builtin_nontemporal_store(vv,
                    reinterpret_cast<floatx4*>(Sb + (size_t)r * Lsz + pair * 80 + c4 * 4));
            }
        };

        dma(0, 0);
        __syncthreads();             // drain: chunk 0 resident
        for (int pr = 0; pr < 5; ++pr) {
            const int ch = 2 * pr;
            // phase A (compute scans ch from buf0): DMA ch+1 -> buf1
            // (buf1 was freed at the barrier that started this phase)
            dma(ch + 1, 1);
            if (pr >= 1) expand_half(pr - 1, 0);
            __syncthreads();
            // phase B (compute scans ch+1 from buf1): DMA ch+2 -> buf0
            if (ch + 2 < 10) dma(ch + 2, 0);
            if (pr >= 1) expand_half(pr - 1, 1);
            __syncthreads();
        }
        expand_half(4, 0); expand_half(4, 1);          // last pair
    } else {
        // ------------------------- compute wave ------------------------
        float v = 0.0f, theta = 1.0f;
        int allow = 0, first = Lsz;
        int cnt_i = 0, swt_i = 0;            // integer-exact reductions
        unsigned int w0, w1, w2;
        const int gl = (lane >> 2) & 7;      // read-side XOR (matches source)

        // scan one 40-step chunk; gb = bit offset within pair (LITERAL 0/40)
        auto scan_chunk = [&](int buf, int t0, int gb) {
            const float* src = &in2[buf][lane * TC];
            float4 rgc4[V4];
#pragma unroll
            for (int j = 0; j < V4; ++j) {           // ds_read_b128, uniform banks
                const int jj = (j < 8) ? (j ^ gl) : j;
                rgc4[j] = *reinterpret_cast<const float4*>(src + jj * 4);
            }
            const float* in = reinterpret_cast<const float*>(rgc4);
#pragma unroll
            for (int c = 0; c < TC; ++c) {
                v = __builtin_fmaf(v, 0.95f, in[c]);       // v += -v/20 + I
                const int t = t0 + c;
                const bool hard = (v >= theta) & (t >= allow);
                v     = hard ? 0.0f : v;
                theta = __builtin_fmaf(theta, 0.98f, hard ? 0.52f : 0.02f);
                allow = hard ? (t + 6) : allow;            // 5 blocked steps
                const int cg = gb + c;                     // compile-time
                const unsigned int m = hard ? (1u << (cg & 31)) : 0u;
                if (cg < 32) w0 |= m; else if (cg < 64) w1 |= m; else w2 |= m;
            }
        };

        __syncthreads();                      // matches memory prologue barrier
        for (int pr = 0; pr < 5; ++pr) {
            w0 = w1 = w2 = 0u;
            scan_chunk(0, 2 * pr * TC, 0);
            __syncthreads();
            scan_chunk(1, (2 * pr + 1) * TC, TC);
            // pair-end reductions (exact) + publish bits for the memory wave
            const int tp = pr * 80;
            const int p0 = __popc(w0), p1 = __popc(w1), p2 = __popc(w2);
            const int cp = p0 + p1 + p2;
            cnt_i += cp;
            swt_i += tp * cp + sumpos(w0) + sumpos(w1) + 32 * p1 +
                     sumpos(w2) + 64 * p2;
            const int cand = w0 ? tp + (__ffs(w0) - 1)
                           : w1 ? tp + 32 + (__ffs(w1) - 1)
                           : w2 ? tp + 64 + (__ffs(w2) - 1) : Lsz;
            first = min(first, cand);
            *reinterpret_cast<uint4*>(&bits[pr & 1][lane * 4]) =
                make_uint4(w0, w1, w2, 0u);
            __syncthreads();
        }
        const int row = rb + lane;
        out[(size_t)Bsz * Lsz + row]       = (float)first;
        out[(size_t)Bsz * Lsz + Bsz + row] = (float)swt_i / ((float)cnt_i + 1e-6f);
    }
}

extern "C" void kernel_launch(void* const* d_in, const int* in_sizes, int n_in,
                              void* d_out, int out_size, void* d_ws, size_t ws_size,
                              hipStream_t stream)
{
    const float* I = (const float*)d_in[0];
    float* out = (float*)d_out;
    lif_kernel<<<dim3(Bsz / ROWS), dim3(2 * ROWS), 0, stream>>>(I, out);
}